// Round 11
// baseline (158.336 us; speedup 1.0000x reference)
//
#include <hip/hip_runtime.h>
#include <hip/hip_bf16.h>

#define TT 1024
#define DD 64
#define MAXREL 16
#define NV 33
#define QBLK 16
#define SCALE 0.125f
#define BH 64

typedef short bf16x8 __attribute__((ext_vector_type(8)));
typedef short bf16x4 __attribute__((ext_vector_type(4)));
typedef float f32x4 __attribute__((ext_vector_type(4)));

#define SBAR() __builtin_amdgcn_sched_barrier(0)

static __device__ inline short f2bf(float f) {
    __hip_bfloat16 h = __float2bfloat16(f);   // RNE; compiler emits v_cvt_pk_bf16_f32
    return *(short*)&h;
}
static __device__ inline float bf2f(short s) {
    union { unsigned u; float f; } x;
    x.u = ((unsigned)(unsigned short)s) << 16;
    return x.f;
}
static __device__ inline bf16x8 pack8(float4 a, float4 b) {
    bf16x8 r;
    r[0]=f2bf(a.x); r[1]=f2bf(a.y); r[2]=f2bf(a.z); r[3]=f2bf(a.w);
    r[4]=f2bf(b.x); r[5]=f2bf(b.y); r[6]=f2bf(b.z); r[7]=f2bf(b.w);
    return r;
}

// ---- pre-kernel 1: K f32 -> bf16 ----
__global__ __launch_bounds__(256)
void convk_kernel(const float* __restrict__ src, short* __restrict__ dst) {
    size_t i = (size_t)blockIdx.x * 256 + threadIdx.x;
    const float4* s = (const float4*)(src + i * 8);
    *(bf16x8*)(dst + i * 8) = pack8(s[0], s[1]);
}

// ---- pre-kernel 2: V [bh][s][d] f32 -> vt [bh][d][s] bf16 ----
__global__ __launch_bounds__(256)
void transv_kernel(const float* __restrict__ v, short* __restrict__ vt) {
    int bh = blockIdx.x >> 4;
    int st = blockIdx.x & 15;
    int wave = threadIdx.x >> 6, lane = threadIdx.x & 63;
    int s0 = st * 64 + wave * 16;
    const float* vp = v + ((size_t)bh * TT + s0) * DD + lane;
    bf16x8 lo, hi;
    #pragma unroll
    for (int e = 0; e < 8; ++e) lo[e] = f2bf(vp[(size_t)e * DD]);
    #pragma unroll
    for (int e = 0; e < 8; ++e) hi[e] = f2bf(vp[(size_t)(e + 8) * DD]);
    short* dp = vt + ((size_t)bh * DD + lane) * TT + s0;
    *(bf16x8*)dp = lo;
    *(bf16x8*)(dp + 8) = hi;
}

__global__ __launch_bounds__(256)
__attribute__((amdgpu_waves_per_eu(4, 4)))
void relattn_kernel(const float* __restrict__ q_g,
                    const short* __restrict__ kb,
                    const short* __restrict__ vt,
                    const float* __restrict__ ek_g,
                    const float* __restrict__ ev_g,
                    float* __restrict__ out_g,
                    float* __restrict__ attn_g) {
    __shared__ __align__(16) char pbuf[QBLK * 2048];     // 32768 B bf16 P, swizzled
    __shared__ float qe_lds[QBLK * NV];                  // holds eqe = exp(qe/8)
    __shared__ float w_lds[QBLK * NV];                   // unnormalized w
    __shared__ float psum_lds[QBLK][4];
    __shared__ float psuf_lds[QBLK][4];
    __shared__ float pmid_lds[QBLK][4];
    __shared__ float inv_lds[QBLK];

    const int t    = threadIdx.x;
    const int bid  = blockIdx.x;
    const int wg   = ((bid & 7) << 9) | (bid >> 3);      // XCD swizzle
    const int bh   = wg >> 6;
    const int q0   = (wg & 63) * QBLK;
    const int wave = t >> 6;
    const int lane = t & 63;
    const int lr   = lane & 15;
    const int akg  = lane >> 4;

    // Q fragment (B operand of swapped MFMA): Q[q0+lr][...]
    bf16x8 qF0, qF1;
    {
        const float* qp = q_g + ((size_t)bh * TT + q0 + lr) * DD + akg * 8;
        float4 a = *(const float4*)qp,        b = *(const float4*)(qp + 4);
        float4 c = *(const float4*)(qp + 32), d = *(const float4*)(qp + 36);
        qF0 = pack8(a, b); qF1 = pack8(c, d);
    }

    // ---- Phase A: zero w; eqe = exp(qe/8) via MFMA (waves 0..2) ----
    for (int i = t; i < QBLK * NV; i += 256) w_lds[i] = 0.f;
    if (wave < 3) {
        int v = wave * 16 + lr; if (v > 32) v = 32;
        const float* ep = ek_g + v * DD + akg * 8;
        float4 a = *(const float4*)ep,        b = *(const float4*)(ep + 4);
        float4 c = *(const float4*)(ep + 32), d = *(const float4*)(ep + 36);
        bf16x8 eF0 = pack8(a, b), eF1 = pack8(c, d);
        f32x4 qacc = {0.f, 0.f, 0.f, 0.f};
        qacc = __builtin_amdgcn_mfma_f32_16x16x32_bf16(eF0, qF0, qacc, 0, 0, 0);
        qacc = __builtin_amdgcn_mfma_f32_16x16x32_bf16(eF1, qF1, qacc, 0, 0, 0);
        #pragma unroll
        for (int j = 0; j < 4; ++j) {
            int vv = wave * 16 + akg * 4 + j;
            if (vv < NV) qe_lds[lr * NV + vv] = __expf(qacc[j] * SCALE);
        }
    }
    __syncthreads();

    // ---- Phase C: swapped QK^T -> e = exp(s)*eqe -> bf16 P + partial sums ----
    {
        const short* kp0 = kb + (size_t)bh * TT * DD
                         + (size_t)(wave * 256 + lr) * DD + akg * 8;
        const int tq = q0 + lr;
        const int X  = (lr & 7) << 4;
        const float eqe_lo = qe_lds[lr * NV];
        const float eqe_hi = qe_lds[lr * NV + 32];
        float sum = 0.f, suff = 0.f, msum = 0.f;

        auto CCOMP = [&](bf16x8 kf0, bf16x8 kf1, int nt) {
            f32x4 acc = {0.f, 0.f, 0.f, 0.f};
            acc = __builtin_amdgcn_mfma_f32_16x16x32_bf16(kf0, qF0, acc, 0, 0, 0);
            acc = __builtin_amdgcn_mfma_f32_16x16x32_bf16(kf1, qF1, acc, 0, 0, 0);
            const int sb = wave * 256 + nt * 16 + akg * 4;
            float ex0 = __expf(acc[0] * SCALE), ex1 = __expf(acc[1] * SCALE);
            float ex2 = __expf(acc[2] * SCALE), ex3 = __expf(acc[3] * SCALE);
            float e0, e1, e2, e3;
            if (sb >= tq + MAXREL) {               // fully suffix
                e0 = ex0 * eqe_hi; e1 = ex1 * eqe_hi;
                e2 = ex2 * eqe_hi; e3 = ex3 * eqe_hi;
                float csum = (e0 + e1) + (e2 + e3);
                sum += csum; suff += csum;
            } else if (sb + 3 <= tq - MAXREL) {    // fully prefix
                e0 = ex0 * eqe_lo; e1 = ex1 * eqe_lo;
                e2 = ex2 * eqe_lo; e3 = ex3 * eqe_lo;
                sum += (e0 + e1) + (e2 + e3);
            } else {                               // diagonal band (rare)
                float ee[4]; float exs[4] = {ex0, ex1, ex2, ex3};
                #pragma unroll
                for (int j = 0; j < 4; ++j) {
                    int dr = sb + j - tq;
                    int dc = dr < -MAXREL ? -MAXREL : (dr > MAXREL ? MAXREL : dr);
                    float v = exs[j] * qe_lds[lr * NV + dc + MAXREL];
                    ee[j] = v;
                    sum += v;
                    if (dr >= MAXREL) suff += v;
                    if (dr > -MAXREL && dr < MAXREL) {
                        w_lds[lr * NV + dr + MAXREL] = v;
                        msum += v;
                    }
                }
                e0 = ee[0]; e1 = ee[1]; e2 = ee[2]; e3 = ee[3];
            }
            bf16x4 p4;
            p4[0] = f2bf(e0); p4[1] = f2bf(e1);
            p4[2] = f2bf(e2); p4[3] = f2bf(e3);
            *(bf16x4*)(pbuf + lr * 2048 + ((2 * sb) ^ X)) = p4;
        };

        // depth-6 rotating prefetch, pinned with sched_barrier(0)
        bf16x8 kA0, kA1, kB0, kB1, kC0, kC1, kD0, kD1, kE0, kE1, kF0, kF1;
        #define KLD(R0, R1, NT) \
            R0 = *(const bf16x8*)(kp0 + (NT) * 1024); \
            R1 = *(const bf16x8*)(kp0 + (NT) * 1024 + 32)
        KLD(kA0, kA1, 0); KLD(kB0, kB1, 1); KLD(kC0, kC1, 2);
        KLD(kD0, kD1, 3); KLD(kE0, kE1, 4); KLD(kF0, kF1, 5);
        SBAR();
        CCOMP(kA0, kA1, 0);  KLD(kA0, kA1, 6);  SBAR();
        CCOMP(kB0, kB1, 1);  KLD(kB0, kB1, 7);  SBAR();
        CCOMP(kC0, kC1, 2);  KLD(kC0, kC1, 8);  SBAR();
        CCOMP(kD0, kD1, 3);  KLD(kD0, kD1, 9);  SBAR();
        CCOMP(kE0, kE1, 4);  KLD(kE0, kE1, 10); SBAR();
        CCOMP(kF0, kF1, 5);  KLD(kF0, kF1, 11); SBAR();
        CCOMP(kA0, kA1, 6);  KLD(kA0, kA1, 12); SBAR();
        CCOMP(kB0, kB1, 7);  KLD(kB0, kB1, 13); SBAR();
        CCOMP(kC0, kC1, 8);  KLD(kC0, kC1, 14); SBAR();
        CCOMP(kD0, kD1, 9);  KLD(kD0, kD1, 15); SBAR();
        CCOMP(kE0, kE1, 10);
        CCOMP(kF0, kF1, 11);
        CCOMP(kA0, kA1, 12);
        CCOMP(kB0, kB1, 13);
        CCOMP(kC0, kC1, 14);
        CCOMP(kD0, kD1, 15);
        #undef KLD

        sum  += __shfl_xor(sum, 16);  sum  += __shfl_xor(sum, 32);
        suff += __shfl_xor(suff, 16); suff += __shfl_xor(suff, 32);
        msum += __shfl_xor(msum, 16); msum += __shfl_xor(msum, 32);
        if (lane < 16) {
            psum_lds[lr][wave] = sum;
            psuf_lds[lr][wave] = suff;
            pmid_lds[lr][wave] = msum;
        }
    }
    __syncthreads();

    // ---- D1: finalize per-row sums ----
    if (t < QBLK) {
        float s  = (psum_lds[t][0] + psum_lds[t][1]) + (psum_lds[t][2] + psum_lds[t][3]);
        float sf = (psuf_lds[t][0] + psuf_lds[t][1]) + (psuf_lds[t][2] + psuf_lds[t][3]);
        float sm = (pmid_lds[t][0] + pmid_lds[t][1]) + (pmid_lds[t][2] + pmid_lds[t][3]);
        inv_lds[t] = 1.0f / s;
        w_lds[t * NV]      = s - sf - sm;   // prefix weight (v=0)
        w_lds[t * NV + 32] = sf;            // suffix weight (v=32)
    }
    __syncthreads();

    // ---- Phase F: out = inv * (P V + w . emb_v), depth-3 V prefetch ----
    {
        const int lc = lane & 15;
        const int dcol = wave * 16 + lc;
        const short* vbase = vt + ((size_t)bh * DD + dcol) * TT + akg * 8;
        const char* pb = pbuf + lc * 2048;
        const int X = (lc & 7) << 4;
        f32x4 acc = {0.f, 0.f, 0.f, 0.f};

        auto FCOMP = [&](bf16x8 v0, bf16x8 v1, bf16x8 v2, bf16x8 v3, int g) {
            bf16x8 a0 = *(const bf16x8*)(pb + (((4*g+0) * 64 + akg * 16) ^ X));
            bf16x8 a1 = *(const bf16x8*)(pb + (((4*g+1) * 64 + akg * 16) ^ X));
            bf16x8 a2 = *(const bf16x8*)(pb + (((4*g+2) * 64 + akg * 16) ^ X));
            bf16x8 a3 = *(const bf16x8*)(pb + (((4*g+3) * 64 + akg * 16) ^ X));
            acc = __builtin_amdgcn_mfma_f32_16x16x32_bf16(a0, v0, acc, 0, 0, 0);
            acc = __builtin_amdgcn_mfma_f32_16x16x32_bf16(a1, v1, acc, 0, 0, 0);
            acc = __builtin_amdgcn_mfma_f32_16x16x32_bf16(a2, v2, acc, 0, 0, 0);
            acc = __builtin_amdgcn_mfma_f32_16x16x32_bf16(a3, v3, acc, 0, 0, 0);
        };

        bf16x8 vA0, vA1, vA2, vA3, vB0, vB1, vB2, vB3, vC0, vC1, vC2, vC3;
        #define VLD(R0, R1, R2, R3, G) \
            R0 = *(const bf16x8*)(vbase + (4*(G)+0) * 32); \
            R1 = *(const bf16x8*)(vbase + (4*(G)+1) * 32); \
            R2 = *(const bf16x8*)(vbase + (4*(G)+2) * 32); \
            R3 = *(const bf16x8*)(vbase + (4*(G)+3) * 32)
        VLD(vA0, vA1, vA2, vA3, 0);
        VLD(vB0, vB1, vB2, vB3, 1);
        VLD(vC0, vC1, vC2, vC3, 2);
        SBAR();
        FCOMP(vA0, vA1, vA2, vA3, 0); VLD(vA0, vA1, vA2, vA3, 3); SBAR();
        FCOMP(vB0, vB1, vB2, vB3, 1); VLD(vB0, vB1, vB2, vB3, 4); SBAR();
        FCOMP(vC0, vC1, vC2, vC3, 2); VLD(vC0, vC1, vC2, vC3, 5); SBAR();
        FCOMP(vA0, vA1, vA2, vA3, 3); VLD(vA0, vA1, vA2, vA3, 6); SBAR();
        FCOMP(vB0, vB1, vB2, vB3, 4); VLD(vB0, vB1, vB2, vB3, 7); SBAR();
        FCOMP(vC0, vC1, vC2, vC3, 5);
        FCOMP(vA0, vA1, vA2, vA3, 6);
        FCOMP(vB0, vB1, vB2, vB3, 7);
        #undef VLD

        const int rb = akg * 4;
        float o0 = acc[0], o1 = acc[1], o2 = acc[2], o3 = acc[3];
        #pragma unroll 8
        for (int v = 0; v < NV; ++v) {
            float ev = ev_g[v * DD + dcol];
            o0 += w_lds[(rb + 0) * NV + v] * ev;
            o1 += w_lds[(rb + 1) * NV + v] * ev;
            o2 += w_lds[(rb + 2) * NV + v] * ev;
            o3 += w_lds[(rb + 3) * NV + v] * ev;
        }
        float* op = out_g + ((size_t)bh * TT + q0 + rb) * DD + dcol;
        op[0 * DD] = o0 * inv_lds[rb + 0];
        op[1 * DD] = o1 * inv_lds[rb + 1];
        op[2 * DD] = o2 * inv_lds[rb + 2];
        op[3 * DD] = o3 * inv_lds[rb + 3];
    }

    // ---- D2: normalized attn write (nontemporal, coalesced) ----
    {
        float* ab = attn_g + ((size_t)bh * TT + q0) * TT;
        #pragma unroll
        for (int j = 0; j < 4; ++j) {
            const int r = wave * 4 + j;
            const float inv = inv_lds[r];
            const int X = (r & 7) << 4;
            #pragma unroll
            for (int i = 0; i < 4; ++i) {
                bf16x4 p4 = *(const bf16x4*)(pbuf + r * 2048 + ((8 * lane + 512 * i) ^ X));
                f32x4 o;
                o[0] = bf2f(p4[0]) * inv; o[1] = bf2f(p4[1]) * inv;
                o[2] = bf2f(p4[2]) * inv; o[3] = bf2f(p4[3]) * inv;
                __builtin_nontemporal_store(o, (f32x4*)(ab + (size_t)r * TT + lane * 4 + 256 * i));
            }
        }
    }
}

extern "C" void kernel_launch(void* const* d_in, const int* in_sizes, int n_in,
                              void* d_out, int out_size, void* d_ws, size_t ws_size,
                              hipStream_t stream) {
    const float* q  = (const float*)d_in[0];
    const float* k  = (const float*)d_in[1];
    const float* v  = (const float*)d_in[2];
    const float* ek = (const float*)d_in[3];
    const float* ev = (const float*)d_in[4];
    float* out  = (float*)d_out;
    float* attn = out + (size_t)BH * TT * DD;

    short* kbuf = (short*)d_ws;
    short* vtb  = kbuf + (size_t)BH * TT * DD;

    convk_kernel<<<dim3(2048), dim3(256), 0, stream>>>(k, kbuf);
    transv_kernel<<<dim3(1024), dim3(256), 0, stream>>>(v, vtb);
    relattn_kernel<<<dim3(4096), dim3(256), 0, stream>>>(q, kbuf, vtb, ek, ev, out, attn);
}

// Round 12
// 142.633 us; speedup vs baseline: 1.1101x; 1.1101x over previous
//
#include <hip/hip_runtime.h>
#include <hip/hip_bf16.h>

#define TT 1024
#define DD 64
#define MAXREL 16
#define NV 33
#define QBLK 16
#define SCALE 0.125f
#define BH 64

typedef short bf16x8 __attribute__((ext_vector_type(8)));
typedef short bf16x4 __attribute__((ext_vector_type(4)));
typedef float f32x4 __attribute__((ext_vector_type(4)));

#define SBAR() __builtin_amdgcn_sched_barrier(0)
// s_waitcnt imm: vmcnt[3:0]|[15:14], expcnt[6:4]=7 (no wait), lgkmcnt[11:8]=15 (no wait)
#define WAITV(N) __builtin_amdgcn_s_waitcnt(0x0F70 | (N))

static __device__ inline void gload16(const void* g, void* l) {
    __builtin_amdgcn_global_load_lds(
        (const __attribute__((address_space(1))) void*)g,
        (__attribute__((address_space(3))) void*)l, 16, 0, 0);
}

static __device__ inline short f2bf(float f) {
    __hip_bfloat16 h = __float2bfloat16(f);
    return *(short*)&h;
}
static __device__ inline float bf2f(short s) {
    union { unsigned u; float f; } x;
    x.u = ((unsigned)(unsigned short)s) << 16;
    return x.f;
}
static __device__ inline bf16x8 pack8(float4 a, float4 b) {
    bf16x8 r;
    r[0]=f2bf(a.x); r[1]=f2bf(a.y); r[2]=f2bf(a.z); r[3]=f2bf(a.w);
    r[4]=f2bf(b.x); r[5]=f2bf(b.y); r[6]=f2bf(b.z); r[7]=f2bf(b.w);
    return r;
}

// ---- pre-kernel 1: K f32 -> bf16 ----
__global__ __launch_bounds__(256)
void convk_kernel(const float* __restrict__ src, short* __restrict__ dst) {
    size_t i = (size_t)blockIdx.x * 256 + threadIdx.x;
    const float4* s = (const float4*)(src + i * 8);
    *(bf16x8*)(dst + i * 8) = pack8(s[0], s[1]);
}

// ---- pre-kernel 2: V [bh][s][d] f32 -> vt [bh][d][s] bf16 ----
__global__ __launch_bounds__(256)
void transv_kernel(const float* __restrict__ v, short* __restrict__ vt) {
    int bh = blockIdx.x >> 4;
    int st = blockIdx.x & 15;
    int wave = threadIdx.x >> 6, lane = threadIdx.x & 63;
    int s0 = st * 64 + wave * 16;
    const float* vp = v + ((size_t)bh * TT + s0) * DD + lane;
    bf16x8 lo, hi;
    #pragma unroll
    for (int e = 0; e < 8; ++e) lo[e] = f2bf(vp[(size_t)e * DD]);
    #pragma unroll
    for (int e = 0; e < 8; ++e) hi[e] = f2bf(vp[(size_t)(e + 8) * DD]);
    short* dp = vt + ((size_t)bh * DD + lane) * TT + s0;
    *(bf16x8*)dp = lo;
    *(bf16x8*)(dp + 8) = hi;
}

__global__ __launch_bounds__(256)
void relattn_kernel(const float* __restrict__ q_g,
                    const short* __restrict__ kb,
                    const short* __restrict__ vt,
                    const float* __restrict__ ek_g,
                    const float* __restrict__ ev_g,
                    float* __restrict__ out_g,
                    float* __restrict__ attn_g) {
    __shared__ __align__(16) char pbuf[QBLK * 2048];     // 32768 B bf16 P, swizzled
    __shared__ __align__(16) char kstage[4 * 4096];      // 16384 B: per-wave K/V stage (2x2KB)
    __shared__ float qe_lds[QBLK * NV];                  // eqe = exp(qe/8)
    __shared__ float w_lds[QBLK * NV];                   // unnormalized w
    __shared__ float psum_lds[QBLK][4];
    __shared__ float psuf_lds[QBLK][4];
    __shared__ float pmid_lds[QBLK][4];
    __shared__ float inv_lds[QBLK];

    const int t    = threadIdx.x;
    const int bid  = blockIdx.x;
    const int wg   = ((bid & 7) << 9) | (bid >> 3);      // XCD swizzle
    const int bh   = wg >> 6;
    const int q0   = (wg & 63) * QBLK;
    const int wave = t >> 6;
    const int lane = t & 63;
    const int lr   = lane & 15;
    const int akg  = lane >> 4;
    const int srl  = lane >> 3;                          // staging row-local 0..7
    const int sqg  = (lane & 7) ^ srl;                   // pre-swizzled quad index

    // Q fragment (B operand of swapped MFMA): Q[q0+lr][...]
    bf16x8 qF0, qF1;
    {
        const float* qp = q_g + ((size_t)bh * TT + q0 + lr) * DD + akg * 8;
        float4 a = *(const float4*)qp,        b = *(const float4*)(qp + 4);
        float4 c = *(const float4*)(qp + 32), d = *(const float4*)(qp + 36);
        qF0 = pack8(a, b); qF1 = pack8(c, d);
    }

    // ---- Phase A: zero w; eqe = exp(qe/8) via MFMA (waves 0..2) ----
    for (int i = t; i < QBLK * NV; i += 256) w_lds[i] = 0.f;
    if (wave < 3) {
        int v = wave * 16 + lr; if (v > 32) v = 32;
        const float* ep = ek_g + v * DD + akg * 8;
        float4 a = *(const float4*)ep,        b = *(const float4*)(ep + 4);
        float4 c = *(const float4*)(ep + 32), d = *(const float4*)(ep + 36);
        bf16x8 eF0 = pack8(a, b), eF1 = pack8(c, d);
        f32x4 qacc = {0.f, 0.f, 0.f, 0.f};
        qacc = __builtin_amdgcn_mfma_f32_16x16x32_bf16(eF0, qF0, qacc, 0, 0, 0);
        qacc = __builtin_amdgcn_mfma_f32_16x16x32_bf16(eF1, qF1, qacc, 0, 0, 0);
        #pragma unroll
        for (int j = 0; j < 4; ++j) {
            int vv = wave * 16 + akg * 4 + j;
            if (vv < NV) qe_lds[lr * NV + vv] = __expf(qacc[j] * SCALE);
        }
    }
    __syncthreads();

    // ---- Phase C: K async-staged to LDS; swapped QK^T -> e -> P + sums ----
    {
        const short* kgbase = kb + (size_t)bh * TT * DD;       // shorts
        char* kst = kstage + wave * 4096;                      // wave-private 2x2KB
        const int tq = q0 + lr;
        const int X  = (lr & 7) << 4;
        const float eqe_lo = qe_lds[lr * NV];
        const float eqe_hi = qe_lds[lr * NV + 32];
        float sum = 0.f, suff = 0.f, msum = 0.f;

        auto CCOMP = [&](bf16x8 kf0, bf16x8 kf1, int nt) {
            f32x4 acc = {0.f, 0.f, 0.f, 0.f};
            acc = __builtin_amdgcn_mfma_f32_16x16x32_bf16(kf0, qF0, acc, 0, 0, 0);
            acc = __builtin_amdgcn_mfma_f32_16x16x32_bf16(kf1, qF1, acc, 0, 0, 0);
            const int sb = wave * 256 + nt * 16 + akg * 4;
            float ex0 = __expf(acc[0] * SCALE), ex1 = __expf(acc[1] * SCALE);
            float ex2 = __expf(acc[2] * SCALE), ex3 = __expf(acc[3] * SCALE);
            float e0, e1, e2, e3;
            if (sb >= tq + MAXREL) {               // fully suffix
                e0 = ex0 * eqe_hi; e1 = ex1 * eqe_hi;
                e2 = ex2 * eqe_hi; e3 = ex3 * eqe_hi;
                float csum = (e0 + e1) + (e2 + e3);
                sum += csum; suff += csum;
            } else if (sb + 3 <= tq - MAXREL) {    // fully prefix
                e0 = ex0 * eqe_lo; e1 = ex1 * eqe_lo;
                e2 = ex2 * eqe_lo; e3 = ex3 * eqe_lo;
                sum += (e0 + e1) + (e2 + e3);
            } else {                               // diagonal band (rare)
                float ee[4]; float exs[4] = {ex0, ex1, ex2, ex3};
                #pragma unroll
                for (int j = 0; j < 4; ++j) {
                    int dr = sb + j - tq;
                    int dc = dr < -MAXREL ? -MAXREL : (dr > MAXREL ? MAXREL : dr);
                    float v = exs[j] * qe_lds[lr * NV + dc + MAXREL];
                    ee[j] = v;
                    sum += v;
                    if (dr >= MAXREL) suff += v;
                    if (dr > -MAXREL && dr < MAXREL) {
                        w_lds[lr * NV + dr + MAXREL] = v;
                        msum += v;
                    }
                }
                e0 = ee[0]; e1 = ee[1]; e2 = ee[2]; e3 = ee[3];
            }
            bf16x4 p4;
            p4[0] = f2bf(e0); p4[1] = f2bf(e1);
            p4[2] = f2bf(e2); p4[3] = f2bf(e3);
            *(bf16x4*)(pbuf + lr * 2048 + ((2 * sb) ^ X)) = p4;
        };

        // stage K tile nt into buffer B (2 x 1KB instrs, pre-swizzled source)
        auto KSTAGE = [&](int B, int NT) {
            const int s0 = wave * 256 + NT * 16;
            gload16(kgbase + (size_t)(s0 + srl) * 64 + sqg * 8,     kst + B * 2048);
            gload16(kgbase + (size_t)(s0 + 8 + srl) * 64 + sqg * 8, kst + B * 2048 + 1024);
        };

        KSTAGE(0, 0); KSTAGE(1, 1);
        #define CITER(B, NT, W, PF) \
            WAITV(W); SBAR(); \
            { bf16x8 kf0 = *(const bf16x8*)(kst + (B)*2048 + lr*128 + ((((akg))  ^(lr&7)) << 4)); \
              bf16x8 kf1 = *(const bf16x8*)(kst + (B)*2048 + lr*128 + ((((akg)+4)^(lr&7)) << 4)); \
              CCOMP(kf0, kf1, (NT)); } \
            SBAR(); \
            if (PF) KSTAGE((B), (NT) + 2)
        CITER(0, 0, 2, 1);  CITER(1, 1, 2, 1);
        CITER(0, 2, 2, 1);  CITER(1, 3, 2, 1);
        CITER(0, 4, 2, 1);  CITER(1, 5, 2, 1);
        CITER(0, 6, 2, 1);  CITER(1, 7, 2, 1);
        CITER(0, 8, 2, 1);  CITER(1, 9, 2, 1);
        CITER(0,10, 2, 1);  CITER(1,11, 2, 1);
        CITER(0,12, 2, 1);  CITER(1,13, 2, 1);
        CITER(0,14, 2, 0);  CITER(1,15, 0, 0);
        #undef CITER

        sum  += __shfl_xor(sum, 16);  sum  += __shfl_xor(sum, 32);
        suff += __shfl_xor(suff, 16); suff += __shfl_xor(suff, 32);
        msum += __shfl_xor(msum, 16); msum += __shfl_xor(msum, 32);
        if (lane < 16) {
            psum_lds[lr][wave] = sum;
            psuf_lds[lr][wave] = suff;
            pmid_lds[lr][wave] = msum;
        }
    }
    __syncthreads();

    // ---- D1: finalize per-row sums ----
    if (t < QBLK) {
        float s  = (psum_lds[t][0] + psum_lds[t][1]) + (psum_lds[t][2] + psum_lds[t][3]);
        float sf = (psuf_lds[t][0] + psuf_lds[t][1]) + (psuf_lds[t][2] + psuf_lds[t][3]);
        float sm = (pmid_lds[t][0] + pmid_lds[t][1]) + (pmid_lds[t][2] + pmid_lds[t][3]);
        inv_lds[t] = 1.0f / s;
        w_lds[t * NV]      = s - sf - sm;   // prefix weight (v=0)
        w_lds[t * NV + 32] = sf;            // suffix weight (v=32)
    }
    __syncthreads();

    // ---- Phase F: V async-staged; out = inv * (P V + w . emb_v) ----
    {
        const int lc = lane & 15;
        const int dcol = wave * 16 + lc;
        const char* pb = pbuf + lc * 2048;
        const int X = (lc & 7) << 4;
        char* vst = kstage + wave * 4096;                      // reuse after barrier
        const short* vgbase = vt + ((size_t)bh * DD + wave * 16) * TT;   // shorts
        f32x4 acc = {0.f, 0.f, 0.f, 0.f};

        // stage V step S (kt = 2S, 2S+1 for all 16 d-rows) into buffer B
        auto VSTAGE = [&](int B, int S) {
            gload16(vgbase + (size_t)srl * TT + S * 64 + sqg * 8,       vst + B * 2048);
            gload16(vgbase + (size_t)(8 + srl) * TT + S * 64 + sqg * 8, vst + B * 2048 + 1024);
        };

        VSTAGE(0, 0); VSTAGE(1, 1);
        #define FITER(B, S, W, PF) \
            WAITV(W); SBAR(); \
            { bf16x8 vf0 = *(const bf16x8*)(vst + (B)*2048 + lc*128 + ((((akg))  ^(lc&7)) << 4)); \
              bf16x8 vf1 = *(const bf16x8*)(vst + (B)*2048 + lc*128 + ((((akg)+4)^(lc&7)) << 4)); \
              bf16x8 a0 = *(const bf16x8*)(pb + (((2*(S))*64     + akg*16) ^ X)); \
              bf16x8 a1 = *(const bf16x8*)(pb + (((2*(S)+1)*64   + akg*16) ^ X)); \
              acc = __builtin_amdgcn_mfma_f32_16x16x32_bf16(a0, vf0, acc, 0, 0, 0); \
              acc = __builtin_amdgcn_mfma_f32_16x16x32_bf16(a1, vf1, acc, 0, 0, 0); } \
            SBAR(); \
            if (PF) VSTAGE((B), (S) + 2)
        FITER(0, 0, 2, 1);  FITER(1, 1, 2, 1);
        FITER(0, 2, 2, 1);  FITER(1, 3, 2, 1);
        FITER(0, 4, 2, 1);  FITER(1, 5, 2, 1);
        FITER(0, 6, 2, 1);  FITER(1, 7, 2, 1);
        FITER(0, 8, 2, 1);  FITER(1, 9, 2, 1);
        FITER(0,10, 2, 1);  FITER(1,11, 2, 1);
        FITER(0,12, 2, 1);  FITER(1,13, 2, 1);
        FITER(0,14, 2, 0);  FITER(1,15, 0, 0);
        #undef FITER

        const int rb = akg * 4;
        float o0 = acc[0], o1 = acc[1], o2 = acc[2], o3 = acc[3];
        #pragma unroll 8
        for (int v = 0; v < NV; ++v) {
            float ev = ev_g[v * DD + dcol];
            o0 += w_lds[(rb + 0) * NV + v] * ev;
            o1 += w_lds[(rb + 1) * NV + v] * ev;
            o2 += w_lds[(rb + 2) * NV + v] * ev;
            o3 += w_lds[(rb + 3) * NV + v] * ev;
        }
        float* op = out_g + ((size_t)bh * TT + q0 + rb) * DD + dcol;
        op[0 * DD] = o0 * inv_lds[rb + 0];
        op[1 * DD] = o1 * inv_lds[rb + 1];
        op[2 * DD] = o2 * inv_lds[rb + 2];
        op[3 * DD] = o3 * inv_lds[rb + 3];
    }

    // ---- D2: normalized attn write (nontemporal, coalesced) ----
    {
        float* ab = attn_g + ((size_t)bh * TT + q0) * TT;
        #pragma unroll
        for (int j = 0; j < 4; ++j) {
            const int r = wave * 4 + j;
            const float inv = inv_lds[r];
            const int X = (r & 7) << 4;
            #pragma unroll
            for (int i = 0; i < 4; ++i) {
                bf16x4 p4 = *(const bf16x4*)(pbuf + r * 2048 + ((8 * lane + 512 * i) ^ X));
                f32x4 o;
                o[0] = bf2f(p4[0]) * inv; o[1] = bf2f(p4[1]) * inv;
                o[2] = bf2f(p4[2]) * inv; o[3] = bf2f(p4[3]) * inv;
                __builtin_nontemporal_store(o, (f32x4*)(ab + (size_t)r * TT + lane * 4 + 256 * i));
            }
        }
    }
}

extern "C" void kernel_launch(void* const* d_in, const int* in_sizes, int n_in,
                              void* d_out, int out_size, void* d_ws, size_t ws_size,
                              hipStream_t stream) {
    const float* q  = (const float*)d_in[0];
    const float* k  = (const float*)d_in[1];
    const float* v  = (const float*)d_in[2];
    const float* ek = (const float*)d_in[3];
    const float* ev = (const float*)d_in[4];
    float* out  = (float*)d_out;
    float* attn = out + (size_t)BH * TT * DD;

    short* kbuf = (short*)d_ws;
    short* vtb  = kbuf + (size_t)BH * TT * DD;

    convk_kernel<<<dim3(2048), dim3(256), 0, stream>>>(k, kbuf);
    transv_kernel<<<dim3(1024), dim3(256), 0, stream>>>(v, vtb);
    relattn_kernel<<<dim3(4096), dim3(256), 0, stream>>>(q, kbuf, vtb, ek, ev, out, attn);
}

// Round 14
// 140.474 us; speedup vs baseline: 1.1272x; 1.0154x over previous
//
#include <hip/hip_runtime.h>
#include <hip/hip_bf16.h>

#define TT 1024
#define DD 64
#define MAXREL 16
#define NV 33
#define QBLK 16
#define SCALE 0.125f
#define BH 64

typedef short bf16x8 __attribute__((ext_vector_type(8)));
typedef short bf16x4 __attribute__((ext_vector_type(4)));
typedef float f32x4 __attribute__((ext_vector_type(4)));

#define SBAR() __builtin_amdgcn_sched_barrier(0)
// s_waitcnt imm: vmcnt[3:0]|[15:14], expcnt[6:4]=7 (no wait), lgkmcnt[11:8]=15 (no wait)
#define WAITV(N) __builtin_amdgcn_s_waitcnt(0x0F70 | (N))

static __device__ inline void gload16(const void* g, void* l) {
    __builtin_amdgcn_global_load_lds(
        (const __attribute__((address_space(1))) void*)g,
        (__attribute__((address_space(3))) void*)l, 16, 0, 0);
}

static __device__ inline short f2bf(float f) {
    __hip_bfloat16 h = __float2bfloat16(f);
    return *(short*)&h;
}
static __device__ inline float bf2f(short s) {
    union { unsigned u; float f; } x;
    x.u = ((unsigned)(unsigned short)s) << 16;
    return x.f;
}
static __device__ inline bf16x8 pack8(float4 a, float4 b) {
    bf16x8 r;
    r[0]=f2bf(a.x); r[1]=f2bf(a.y); r[2]=f2bf(a.z); r[3]=f2bf(a.w);
    r[4]=f2bf(b.x); r[5]=f2bf(b.y); r[6]=f2bf(b.z); r[7]=f2bf(b.w);
    return r;
}

// ---- pre-kernel 1: K f32 -> bf16 ----
__global__ __launch_bounds__(256)
void convk_kernel(const float* __restrict__ src, short* __restrict__ dst) {
    size_t i = (size_t)blockIdx.x * 256 + threadIdx.x;
    const float4* s = (const float4*)(src + i * 8);
    *(bf16x8*)(dst + i * 8) = pack8(s[0], s[1]);
}

// ---- pre-kernel 2: V [bh][s][d] f32 -> vt [bh][d][s] bf16 ----
__global__ __launch_bounds__(256)
void transv_kernel(const float* __restrict__ v, short* __restrict__ vt) {
    int bh = blockIdx.x >> 4;
    int st = blockIdx.x & 15;
    int wave = threadIdx.x >> 6, lane = threadIdx.x & 63;
    int s0 = st * 64 + wave * 16;
    const float* vp = v + ((size_t)bh * TT + s0) * DD + lane;
    bf16x8 lo, hi;
    #pragma unroll
    for (int e = 0; e < 8; ++e) lo[e] = f2bf(vp[(size_t)e * DD]);
    #pragma unroll
    for (int e = 0; e < 8; ++e) hi[e] = f2bf(vp[(size_t)(e + 8) * DD]);
    short* dp = vt + ((size_t)bh * DD + lane) * TT + s0;
    *(bf16x8*)dp = lo;
    *(bf16x8*)(dp + 8) = hi;
}

__global__ __launch_bounds__(256)
void relattn_kernel(const float* __restrict__ q_g,
                    const short* __restrict__ kb,
                    const short* __restrict__ vt,
                    const float* __restrict__ ek_g,
                    const float* __restrict__ ev_g,
                    float* __restrict__ out_g,
                    float* __restrict__ attn_g) {
    __shared__ __align__(16) char pbuf[QBLK * 2048];     // 32768 B bf16 P, swizzled
    __shared__ __align__(16) char kstage[4 * 4096];      // 16384 B: per-wave K/V stage (2x2KB)
    __shared__ float qe_lds[QBLK * NV];                  // eqe = exp(qe/8)
    __shared__ float w_lds[QBLK * NV];                   // unnormalized w
    __shared__ float psum_lds[QBLK][4];
    __shared__ float psuf_lds[QBLK][4];
    __shared__ float pmid_lds[QBLK][4];
    __shared__ float inv_lds[QBLK];

    const int t    = threadIdx.x;
    const int bid  = blockIdx.x;
    const int wg   = ((bid & 7) << 9) | (bid >> 3);      // XCD swizzle
    const int bh   = wg >> 6;
    const int q0   = (wg & 63) * QBLK;
    const int wave = t >> 6;
    const int lane = t & 63;
    const int lr   = lane & 15;
    const int akg  = lane >> 4;
    const int srl  = lane >> 3;                          // staging row-local 0..7
    const int sqg  = (lane & 7) ^ srl;                   // pre-swizzled quad index

    // Q fragment (B operand of swapped MFMA): Q[q0+lr][...]
    bf16x8 qF0, qF1;
    {
        const float* qp = q_g + ((size_t)bh * TT + q0 + lr) * DD + akg * 8;
        float4 a = *(const float4*)qp,        b = *(const float4*)(qp + 4);
        float4 c = *(const float4*)(qp + 32), d = *(const float4*)(qp + 36);
        qF0 = pack8(a, b); qF1 = pack8(c, d);
    }

    // ---- Phase A: zero w; eqe = exp(qe/8) via MFMA (waves 0..2) ----
    for (int i = t; i < QBLK * NV; i += 256) w_lds[i] = 0.f;
    if (wave < 3) {
        int v = wave * 16 + lr; if (v > 32) v = 32;
        const float* ep = ek_g + v * DD + akg * 8;
        float4 a = *(const float4*)ep,        b = *(const float4*)(ep + 4);
        float4 c = *(const float4*)(ep + 32), d = *(const float4*)(ep + 36);
        bf16x8 eF0 = pack8(a, b), eF1 = pack8(c, d);
        f32x4 qacc = {0.f, 0.f, 0.f, 0.f};
        qacc = __builtin_amdgcn_mfma_f32_16x16x32_bf16(eF0, qF0, qacc, 0, 0, 0);
        qacc = __builtin_amdgcn_mfma_f32_16x16x32_bf16(eF1, qF1, qacc, 0, 0, 0);
        #pragma unroll
        for (int j = 0; j < 4; ++j) {
            int vv = wave * 16 + akg * 4 + j;
            if (vv < NV) qe_lds[lr * NV + vv] = __expf(qacc[j] * SCALE);
        }
    }
    __syncthreads();

    // ---- Phase C: K async-staged; CVALU(n-1) overlapped under ds_read(n) ----
    {
        const short* kgbase = kb + (size_t)bh * TT * DD;       // shorts
        char* kst = kstage + wave * 4096;                      // wave-private 2x2KB
        const int tq = q0 + lr;
        const int X  = (lr & 7) << 4;
        const float eqe_lo = qe_lds[lr * NV];
        const float eqe_hi = qe_lds[lr * NV + 32];
        float sum = 0.f, suff = 0.f, msum = 0.f;

        // post-MFMA VALU for tile nt (register-only until final P store)
        auto CVALU = [&](f32x4 acc, int nt) {
            const int sb = wave * 256 + nt * 16 + akg * 4;
            float ex0 = __expf(acc[0] * SCALE), ex1 = __expf(acc[1] * SCALE);
            float ex2 = __expf(acc[2] * SCALE), ex3 = __expf(acc[3] * SCALE);
            float e0, e1, e2, e3;
            if (sb >= tq + MAXREL) {               // fully suffix
                e0 = ex0 * eqe_hi; e1 = ex1 * eqe_hi;
                e2 = ex2 * eqe_hi; e3 = ex3 * eqe_hi;
                float csum = (e0 + e1) + (e2 + e3);
                sum += csum; suff += csum;
            } else if (sb + 3 <= tq - MAXREL) {    // fully prefix
                e0 = ex0 * eqe_lo; e1 = ex1 * eqe_lo;
                e2 = ex2 * eqe_lo; e3 = ex3 * eqe_lo;
                sum += (e0 + e1) + (e2 + e3);
            } else {                               // diagonal band (rare)
                float ee[4]; float exs[4] = {ex0, ex1, ex2, ex3};
                #pragma unroll
                for (int j = 0; j < 4; ++j) {
                    int dr = sb + j - tq;
                    int dc = dr < -MAXREL ? -MAXREL : (dr > MAXREL ? MAXREL : dr);
                    float v = exs[j] * qe_lds[lr * NV + dc + MAXREL];
                    ee[j] = v;
                    sum += v;
                    if (dr >= MAXREL) suff += v;
                    if (dr > -MAXREL && dr < MAXREL) {
                        w_lds[lr * NV + dr + MAXREL] = v;
                        msum += v;
                    }
                }
                e0 = ee[0]; e1 = ee[1]; e2 = ee[2]; e3 = ee[3];
            }
            bf16x4 p4;
            p4[0] = f2bf(e0); p4[1] = f2bf(e1);
            p4[2] = f2bf(e2); p4[3] = f2bf(e3);
            *(bf16x4*)(pbuf + lr * 2048 + ((2 * sb) ^ X)) = p4;
        };

        auto MFMA2 = [&](bf16x8 kf0, bf16x8 kf1) {
            f32x4 acc = {0.f, 0.f, 0.f, 0.f};
            __builtin_amdgcn_s_setprio(1);
            acc = __builtin_amdgcn_mfma_f32_16x16x32_bf16(kf0, qF0, acc, 0, 0, 0);
            acc = __builtin_amdgcn_mfma_f32_16x16x32_bf16(kf1, qF1, acc, 0, 0, 0);
            __builtin_amdgcn_s_setprio(0);
            return acc;
        };

        auto KSTAGE = [&](int B, int NT) {
            const int s0 = wave * 256 + NT * 16;
            gload16(kgbase + (size_t)(s0 + srl) * 64 + sqg * 8,     kst + B * 2048);
            gload16(kgbase + (size_t)(s0 + 8 + srl) * 64 + sqg * 8, kst + B * 2048 + 1024);
        };

        KSTAGE(0, 0); KSTAGE(1, 1);
        f32x4 aA, aB;
        // Region layout identical to R12 (KSTAGE in its own post-SBAR region);
        // only change: CVALU(prev) moved into the compute region before MFMA.
        #define CITER(B, NT, W, PF, AC, AP, NP) \
            WAITV(W); SBAR(); \
            { bf16x8 kf0 = *(const bf16x8*)(kst + (B)*2048 + lr*128 + ((((akg))  ^(lr&7)) << 4)); \
              bf16x8 kf1 = *(const bf16x8*)(kst + (B)*2048 + lr*128 + ((((akg)+4)^(lr&7)) << 4)); \
              if ((NP) >= 0) CVALU(AP, NP); \
              AC = MFMA2(kf0, kf1); } \
            SBAR(); \
            if (PF) KSTAGE((B), (NT) + 2)
        CITER(0, 0, 2, 1, aA, aB, -1);
        CITER(1, 1, 2, 1, aB, aA,  0);
        CITER(0, 2, 2, 1, aA, aB,  1);
        CITER(1, 3, 2, 1, aB, aA,  2);
        CITER(0, 4, 2, 1, aA, aB,  3);
        CITER(1, 5, 2, 1, aB, aA,  4);
        CITER(0, 6, 2, 1, aA, aB,  5);
        CITER(1, 7, 2, 1, aB, aA,  6);
        CITER(0, 8, 2, 1, aA, aB,  7);
        CITER(1, 9, 2, 1, aB, aA,  8);
        CITER(0,10, 2, 1, aA, aB,  9);
        CITER(1,11, 2, 1, aB, aA, 10);
        CITER(0,12, 2, 1, aA, aB, 11);
        CITER(1,13, 2, 1, aB, aA, 12);
        CITER(0,14, 2, 0, aA, aB, 13);
        CITER(1,15, 0, 0, aB, aA, 14);
        CVALU(aB, 15);
        #undef CITER

        sum  += __shfl_xor(sum, 16);  sum  += __shfl_xor(sum, 32);
        suff += __shfl_xor(suff, 16); suff += __shfl_xor(suff, 32);
        msum += __shfl_xor(msum, 16); msum += __shfl_xor(msum, 32);
        if (lane < 16) {
            psum_lds[lr][wave] = sum;
            psuf_lds[lr][wave] = suff;
            pmid_lds[lr][wave] = msum;
        }
    }
    __syncthreads();

    // ---- D1: finalize per-row sums ----
    if (t < QBLK) {
        float s  = (psum_lds[t][0] + psum_lds[t][1]) + (psum_lds[t][2] + psum_lds[t][3]);
        float sf = (psuf_lds[t][0] + psuf_lds[t][1]) + (psuf_lds[t][2] + psuf_lds[t][3]);
        float sm = (pmid_lds[t][0] + pmid_lds[t][1]) + (pmid_lds[t][2] + pmid_lds[t][3]);
        inv_lds[t] = 1.0f / s;
        w_lds[t * NV]      = s - sf - sm;   // prefix weight (v=0)
        w_lds[t * NV + 32] = sf;            // suffix weight (v=32)
    }
    __syncthreads();

    // ---- Phase F: V async-staged (R12 region layout); dual accumulators ----
    {
        const int lc = lane & 15;
        const int dcol = wave * 16 + lc;
        const char* pb = pbuf + lc * 2048;
        const int X = (lc & 7) << 4;
        char* vst = kstage + wave * 4096;                      // reuse after barrier
        const short* vgbase = vt + ((size_t)bh * DD + wave * 16) * TT;   // shorts
        f32x4 acc0 = {0.f, 0.f, 0.f, 0.f};
        f32x4 acc1 = {0.f, 0.f, 0.f, 0.f};

        auto VSTAGE = [&](int B, int S) {
            gload16(vgbase + (size_t)srl * TT + S * 64 + sqg * 8,       vst + B * 2048);
            gload16(vgbase + (size_t)(8 + srl) * TT + S * 64 + sqg * 8, vst + B * 2048 + 1024);
        };

        VSTAGE(0, 0); VSTAGE(1, 1);
        #define FITER(B, S, W, PF, AC) \
            WAITV(W); SBAR(); \
            { bf16x8 vf0 = *(const bf16x8*)(vst + (B)*2048 + lc*128 + ((((akg))  ^(lc&7)) << 4)); \
              bf16x8 vf1 = *(const bf16x8*)(vst + (B)*2048 + lc*128 + ((((akg)+4)^(lc&7)) << 4)); \
              bf16x8 a0 = *(const bf16x8*)(pb + (((2*(S))*64     + akg*16) ^ X)); \
              bf16x8 a1 = *(const bf16x8*)(pb + (((2*(S)+1)*64   + akg*16) ^ X)); \
              __builtin_amdgcn_s_setprio(1); \
              AC = __builtin_amdgcn_mfma_f32_16x16x32_bf16(a0, vf0, AC, 0, 0, 0); \
              AC = __builtin_amdgcn_mfma_f32_16x16x32_bf16(a1, vf1, AC, 0, 0, 0); \
              __builtin_amdgcn_s_setprio(0); } \
            SBAR(); \
            if (PF) VSTAGE((B), (S) + 2)
        FITER(0, 0, 2, 1, acc0);  FITER(1, 1, 2, 1, acc1);
        FITER(0, 2, 2, 1, acc0);  FITER(1, 3, 2, 1, acc1);
        FITER(0, 4, 2, 1, acc0);  FITER(1, 5, 2, 1, acc1);
        FITER(0, 6, 2, 1, acc0);  FITER(1, 7, 2, 1, acc1);
        FITER(0, 8, 2, 1, acc0);  FITER(1, 9, 2, 1, acc1);
        FITER(0,10, 2, 1, acc0);  FITER(1,11, 2, 1, acc1);
        FITER(0,12, 2, 1, acc0);  FITER(1,13, 2, 1, acc1);
        FITER(0,14, 2, 0, acc0);  FITER(1,15, 0, 0, acc1);
        #undef FITER

        f32x4 acc;
        acc[0] = acc0[0] + acc1[0]; acc[1] = acc0[1] + acc1[1];
        acc[2] = acc0[2] + acc1[2]; acc[3] = acc0[3] + acc1[3];

        const int rb = akg * 4;
        float o0 = acc[0], o1 = acc[1], o2 = acc[2], o3 = acc[3];
        #pragma unroll 8
        for (int v = 0; v < NV; ++v) {
            float ev = ev_g[v * DD + dcol];
            o0 += w_lds[(rb + 0) * NV + v] * ev;
            o1 += w_lds[(rb + 1) * NV + v] * ev;
            o2 += w_lds[(rb + 2) * NV + v] * ev;
            o3 += w_lds[(rb + 3) * NV + v] * ev;
        }
        float* op = out_g + ((size_t)bh * TT + q0 + rb) * DD + dcol;
        op[0 * DD] = o0 * inv_lds[rb + 0];
        op[1 * DD] = o1 * inv_lds[rb + 1];
        op[2 * DD] = o2 * inv_lds[rb + 2];
        op[3 * DD] = o3 * inv_lds[rb + 3];
    }

    // ---- D2: normalized attn write (nontemporal, coalesced) ----
    {
        float* ab = attn_g + ((size_t)bh * TT + q0) * TT;
        #pragma unroll
        for (int j = 0; j < 4; ++j) {
            const int r = wave * 4 + j;
            const float inv = inv_lds[r];
            const int X = (r & 7) << 4;
            #pragma unroll
            for (int i = 0; i < 4; ++i) {
                bf16x4 p4 = *(const bf16x4*)(pbuf + r * 2048 + ((8 * lane + 512 * i) ^ X));
                f32x4 o;
                o[0] = bf2f(p4[0]) * inv; o[1] = bf2f(p4[1]) * inv;
                o[2] = bf2f(p4[2]) * inv; o[3] = bf2f(p4[3]) * inv;
                __builtin_nontemporal_store(o, (f32x4*)(ab + (size_t)r * TT + lane * 4 + 256 * i));
            }
        }
    }
}

extern "C" void kernel_launch(void* const* d_in, const int* in_sizes, int n_in,
                              void* d_out, int out_size, void* d_ws, size_t ws_size,
                              hipStream_t stream) {
    const float* q  = (const float*)d_in[0];
    const float* k  = (const float*)d_in[1];
    const float* v  = (const float*)d_in[2];
    const float* ek = (const float*)d_in[3];
    const float* ev = (const float*)d_in[4];
    float* out  = (float*)d_out;
    float* attn = out + (size_t)BH * TT * DD;

    short* kbuf = (short*)d_ws;
    short* vtb  = kbuf + (size_t)BH * TT * DD;

    convk_kernel<<<dim3(2048), dim3(256), 0, stream>>>(k, kbuf);
    transv_kernel<<<dim3(1024), dim3(256), 0, stream>>>(v, vtb);
    relattn_kernel<<<dim3(4096), dim3(256), 0, stream>>>(q, kbuf, vtb, ek, ev, out, attn);
}

// Round 15
// 138.897 us; speedup vs baseline: 1.1400x; 1.0114x over previous
//
#include <hip/hip_runtime.h>
#include <hip/hip_bf16.h>

#define TT 1024
#define DD 64
#define MAXREL 16
#define NV 33
#define QBLK 16
#define SCALE 0.125f
#define BH 64

typedef short bf16x8 __attribute__((ext_vector_type(8)));
typedef short bf16x4 __attribute__((ext_vector_type(4)));
typedef float f32x4 __attribute__((ext_vector_type(4)));

#define SBAR() __builtin_amdgcn_sched_barrier(0)
// s_waitcnt imm: vmcnt[3:0]|[15:14], expcnt[6:4], lgkmcnt[11:8]
#define WAITV(N)   __builtin_amdgcn_s_waitcnt(0x0F70 | (N))   // lgkm=15, exp=7, vm=N
#define WAITLGKM() __builtin_amdgcn_s_waitcnt(0xC07F)          // vm=63, exp=7, lgkm=0

static __device__ inline void gload16(const void* g, void* l) {
    __builtin_amdgcn_global_load_lds(
        (const __attribute__((address_space(1))) void*)g,
        (__attribute__((address_space(3))) void*)l, 16, 0, 0);
}

static __device__ inline short f2bf(float f) {
    __hip_bfloat16 h = __float2bfloat16(f);
    return *(short*)&h;
}
static __device__ inline float bf2f(short s) {
    union { unsigned u; float f; } x;
    x.u = ((unsigned)(unsigned short)s) << 16;
    return x.f;
}
static __device__ inline bf16x8 pack8(float4 a, float4 b) {
    bf16x8 r;
    r[0]=f2bf(a.x); r[1]=f2bf(a.y); r[2]=f2bf(a.z); r[3]=f2bf(a.w);
    r[4]=f2bf(b.x); r[5]=f2bf(b.y); r[6]=f2bf(b.z); r[7]=f2bf(b.w);
    return r;
}

// ---- pre-kernel 1: K f32 -> bf16 ----
__global__ __launch_bounds__(256)
void convk_kernel(const float* __restrict__ src, short* __restrict__ dst) {
    size_t i = (size_t)blockIdx.x * 256 + threadIdx.x;
    const float4* s = (const float4*)(src + i * 8);
    *(bf16x8*)(dst + i * 8) = pack8(s[0], s[1]);
}

// ---- pre-kernel 2: V [bh][s][d] f32 -> vt [bh][d][s] bf16 ----
__global__ __launch_bounds__(256)
void transv_kernel(const float* __restrict__ v, short* __restrict__ vt) {
    int bh = blockIdx.x >> 4;
    int st = blockIdx.x & 15;
    int wave = threadIdx.x >> 6, lane = threadIdx.x & 63;
    int s0 = st * 64 + wave * 16;
    const float* vp = v + ((size_t)bh * TT + s0) * DD + lane;
    bf16x8 lo, hi;
    #pragma unroll
    for (int e = 0; e < 8; ++e) lo[e] = f2bf(vp[(size_t)e * DD]);
    #pragma unroll
    for (int e = 0; e < 8; ++e) hi[e] = f2bf(vp[(size_t)(e + 8) * DD]);
    short* dp = vt + ((size_t)bh * DD + lane) * TT + s0;
    *(bf16x8*)dp = lo;
    *(bf16x8*)(dp + 8) = hi;
}

__global__ __launch_bounds__(256)
void relattn_kernel(const float* __restrict__ q_g,
                    const short* __restrict__ kb,
                    const short* __restrict__ vt,
                    const float* __restrict__ ek_g,
                    const float* __restrict__ ev_g,
                    float* __restrict__ out_g,
                    float* __restrict__ attn_g) {
    __shared__ __align__(16) char pbuf[QBLK * 2048];     // 32768 B bf16 P, swizzled
    __shared__ __align__(16) char kstage[4 * 4096];      // per-wave K/V stage (2x2KB)
    __shared__ float qe_lds[QBLK * NV];                  // eqe = exp(qe/8)
    __shared__ float w_lds[QBLK * NV];                   // unnormalized w
    __shared__ float psum_lds[QBLK][4];
    __shared__ float psuf_lds[QBLK][4];
    __shared__ float pmid_lds[QBLK][4];
    __shared__ float inv_lds[QBLK];

    const int t    = threadIdx.x;
    const int bid  = blockIdx.x;
    const int wg   = ((bid & 7) << 9) | (bid >> 3);      // XCD swizzle
    const int bh   = wg >> 6;
    const int q0   = (wg & 63) * QBLK;
    const int wave = t >> 6;
    const int lane = t & 63;
    const int lr   = lane & 15;
    const int akg  = lane >> 4;
    const int srl  = lane >> 3;                          // staging row-local 0..7
    const int sqg  = (lane & 7) ^ srl;                   // pre-swizzled quad index

    const short* kgbase = kb + (size_t)bh * TT * DD;
    char* kst = kstage + wave * 4096;                    // wave-private 2x2KB

    auto KSTAGE = [&](int B, int NT) {
        const int s0 = wave * 256 + NT * 16;
        gload16(kgbase + (size_t)(s0 + srl) * 64 + sqg * 8,     kst + B * 2048);
        gload16(kgbase + (size_t)(s0 + 8 + srl) * 64 + sqg * 8, kst + B * 2048 + 1024);
    };

    // Q fragment (B operand of swapped MFMA): Q[q0+lr][...]
    bf16x8 qF0, qF1;
    {
        const float* qp = q_g + ((size_t)bh * TT + q0 + lr) * DD + akg * 8;
        float4 a = *(const float4*)qp,        b = *(const float4*)(qp + 4);
        float4 c = *(const float4*)(qp + 32), d = *(const float4*)(qp + 36);
        qF0 = pack8(a, b); qF1 = pack8(c, d);
    }

    // Prologue hoist: stage first two K tiles; Phase A + its barrier cover latency
    KSTAGE(0, 0); KSTAGE(1, 1);

    // ---- Phase A: zero w; eqe = exp(qe/8) via MFMA (waves 0..2) ----
    for (int i = t; i < QBLK * NV; i += 256) w_lds[i] = 0.f;
    if (wave < 3) {
        int v = wave * 16 + lr; if (v > 32) v = 32;
        const float* ep = ek_g + v * DD + akg * 8;
        float4 a = *(const float4*)ep,        b = *(const float4*)(ep + 4);
        float4 c = *(const float4*)(ep + 32), d = *(const float4*)(ep + 36);
        bf16x8 eF0 = pack8(a, b), eF1 = pack8(c, d);
        f32x4 qacc = {0.f, 0.f, 0.f, 0.f};
        qacc = __builtin_amdgcn_mfma_f32_16x16x32_bf16(eF0, qF0, qacc, 0, 0, 0);
        qacc = __builtin_amdgcn_mfma_f32_16x16x32_bf16(eF1, qF1, qacc, 0, 0, 0);
        #pragma unroll
        for (int j = 0; j < 4; ++j) {
            int vv = wave * 16 + akg * 4 + j;
            if (vv < NV) qe_lds[lr * NV + vv] = __expf(qacc[j] * SCALE);
        }
    }
    __syncthreads();

    // ---- Phase C ----
    {
        const int tq = q0 + lr;
        const int X  = (lr & 7) << 4;
        const float eqe_lo = qe_lds[lr * NV];
        const float eqe_hi = qe_lds[lr * NV + 32];
        float sum = 0.f, suff = 0.f, msum = 0.f;

        auto CVALU = [&](f32x4 acc, int nt) {
            const int sb = wave * 256 + nt * 16 + akg * 4;
            float ex0 = __expf(acc[0] * SCALE), ex1 = __expf(acc[1] * SCALE);
            float ex2 = __expf(acc[2] * SCALE), ex3 = __expf(acc[3] * SCALE);
            float e0, e1, e2, e3;
            if (sb >= tq + MAXREL) {               // fully suffix
                e0 = ex0 * eqe_hi; e1 = ex1 * eqe_hi;
                e2 = ex2 * eqe_hi; e3 = ex3 * eqe_hi;
                float csum = (e0 + e1) + (e2 + e3);
                sum += csum; suff += csum;
            } else if (sb + 3 <= tq - MAXREL) {    // fully prefix
                e0 = ex0 * eqe_lo; e1 = ex1 * eqe_lo;
                e2 = ex2 * eqe_lo; e3 = ex3 * eqe_lo;
                sum += (e0 + e1) + (e2 + e3);
            } else {                               // diagonal band (rare)
                float ee[4]; float exs[4] = {ex0, ex1, ex2, ex3};
                #pragma unroll
                for (int j = 0; j < 4; ++j) {
                    int dr = sb + j - tq;
                    int dc = dr < -MAXREL ? -MAXREL : (dr > MAXREL ? MAXREL : dr);
                    float v = exs[j] * qe_lds[lr * NV + dc + MAXREL];
                    ee[j] = v;
                    sum += v;
                    if (dr >= MAXREL) suff += v;
                    if (dr > -MAXREL && dr < MAXREL) {
                        w_lds[lr * NV + dr + MAXREL] = v;
                        msum += v;
                    }
                }
                e0 = ee[0]; e1 = ee[1]; e2 = ee[2]; e3 = ee[3];
            }
            bf16x4 p4;
            p4[0] = f2bf(e0); p4[1] = f2bf(e1);
            p4[2] = f2bf(e2); p4[3] = f2bf(e3);
            *(bf16x4*)(pbuf + lr * 2048 + ((2 * sb) ^ X)) = p4;
        };

        auto MFMA2 = [&](bf16x8 kf0, bf16x8 kf1) {
            f32x4 acc = {0.f, 0.f, 0.f, 0.f};
            acc = __builtin_amdgcn_mfma_f32_16x16x32_bf16(kf0, qF0, acc, 0, 0, 0);
            acc = __builtin_amdgcn_mfma_f32_16x16x32_bf16(kf1, qF1, acc, 0, 0, 0);
            return acc;
        };

        f32x4 aA, aB;
        // ds_read -> CVALU(prev) -> lgkm-drain -> SBAR -> stage next -> MFMA
        #define CITER(B, NT, W, PF, AC, AP, NP) \
            WAITV(W); SBAR(); \
            { bf16x8 kf0 = *(const bf16x8*)(kst + (B)*2048 + lr*128 + ((((akg))  ^(lr&7)) << 4)); \
              bf16x8 kf1 = *(const bf16x8*)(kst + (B)*2048 + lr*128 + ((((akg)+4)^(lr&7)) << 4)); \
              if ((NP) >= 0) CVALU(AP, NP); \
              WAITLGKM(); SBAR(); \
              if (PF) KSTAGE((B), (NT) + 2); \
              AC = MFMA2(kf0, kf1); } \
            SBAR()
        CITER(0, 0, 2, 1, aA, aB, -1);
        CITER(1, 1, 2, 1, aB, aA,  0);
        CITER(0, 2, 2, 1, aA, aB,  1);
        CITER(1, 3, 2, 1, aB, aA,  2);
        CITER(0, 4, 2, 1, aA, aB,  3);
        CITER(1, 5, 2, 1, aB, aA,  4);
        CITER(0, 6, 2, 1, aA, aB,  5);
        CITER(1, 7, 2, 1, aB, aA,  6);
        CITER(0, 8, 2, 1, aA, aB,  7);
        CITER(1, 9, 2, 1, aB, aA,  8);
        CITER(0,10, 2, 1, aA, aB,  9);
        CITER(1,11, 2, 1, aB, aA, 10);
        CITER(0,12, 2, 1, aA, aB, 11);
        CITER(1,13, 2, 1, aB, aA, 12);
        CITER(0,14, 2, 0, aA, aB, 13);
        CITER(1,15, 0, 0, aB, aA, 14);
        CVALU(aB, 15);
        #undef CITER

        // Prologue hoist for F: stage first two V tiles into the (wave-private,
        // fully-consumed) kstage region; reduction + barriers + D1 cover latency.
        {
            WAITLGKM(); SBAR();
            const short* vgbase = vt + ((size_t)bh * DD + wave * 16) * TT;
            gload16(vgbase + (size_t)srl * TT + 0 * 64 + sqg * 8,       kst);
            gload16(vgbase + (size_t)(8 + srl) * TT + 0 * 64 + sqg * 8, kst + 1024);
            gload16(vgbase + (size_t)srl * TT + 1 * 64 + sqg * 8,       kst + 2048);
            gload16(vgbase + (size_t)(8 + srl) * TT + 1 * 64 + sqg * 8, kst + 3072);
        }

        sum  += __shfl_xor(sum, 16);  sum  += __shfl_xor(sum, 32);
        suff += __shfl_xor(suff, 16); suff += __shfl_xor(suff, 32);
        msum += __shfl_xor(msum, 16); msum += __shfl_xor(msum, 32);
        if (lane < 16) {
            psum_lds[lr][wave] = sum;
            psuf_lds[lr][wave] = suff;
            pmid_lds[lr][wave] = msum;
        }
    }
    __syncthreads();

    // ---- D1: finalize per-row sums ----
    if (t < QBLK) {
        float s  = (psum_lds[t][0] + psum_lds[t][1]) + (psum_lds[t][2] + psum_lds[t][3]);
        float sf = (psuf_lds[t][0] + psuf_lds[t][1]) + (psuf_lds[t][2] + psuf_lds[t][3]);
        float sm = (pmid_lds[t][0] + pmid_lds[t][1]) + (pmid_lds[t][2] + pmid_lds[t][3]);
        inv_lds[t] = 1.0f / s;
        w_lds[t * NV]      = s - sf - sm;   // prefix weight (v=0)
        w_lds[t * NV + 32] = sf;            // suffix weight (v=32)
    }
    __syncthreads();

    // ---- Phase F: V async-staged; dual accumulators ----
    {
        const int lc = lane & 15;
        const int dcol = wave * 16 + lc;
        const char* pb = pbuf + lc * 2048;
        const int X = (lc & 7) << 4;
        char* vst = kst;
        const short* vgbase = vt + ((size_t)bh * DD + wave * 16) * TT;
        f32x4 acc0 = {0.f, 0.f, 0.f, 0.f};
        f32x4 acc1 = {0.f, 0.f, 0.f, 0.f};

        auto VSTAGE = [&](int B, int S) {
            gload16(vgbase + (size_t)srl * TT + S * 64 + sqg * 8,       vst + B * 2048);
            gload16(vgbase + (size_t)(8 + srl) * TT + S * 64 + sqg * 8, vst + B * 2048 + 1024);
        };

        #define FITER(B, S, W, PF, AC) \
            WAITV(W); SBAR(); \
            { bf16x8 vf0 = *(const bf16x8*)(vst + (B)*2048 + lc*128 + ((((akg))  ^(lc&7)) << 4)); \
              bf16x8 vf1 = *(const bf16x8*)(vst + (B)*2048 + lc*128 + ((((akg)+4)^(lc&7)) << 4)); \
              bf16x8 a0 = *(const bf16x8*)(pb + (((2*(S))*64     + akg*16) ^ X)); \
              bf16x8 a1 = *(const bf16x8*)(pb + (((2*(S)+1)*64   + akg*16) ^ X)); \
              WAITLGKM(); SBAR(); \
              if (PF) VSTAGE((B), (S) + 2); \
              AC = __builtin_amdgcn_mfma_f32_16x16x32_bf16(a0, vf0, AC, 0, 0, 0); \
              AC = __builtin_amdgcn_mfma_f32_16x16x32_bf16(a1, vf1, AC, 0, 0, 0); } \
            SBAR()
        FITER(0, 0, 2, 1, acc0);  FITER(1, 1, 2, 1, acc1);
        FITER(0, 2, 2, 1, acc0);  FITER(1, 3, 2, 1, acc1);
        FITER(0, 4, 2, 1, acc0);  FITER(1, 5, 2, 1, acc1);
        FITER(0, 6, 2, 1, acc0);  FITER(1, 7, 2, 1, acc1);
        FITER(0, 8, 2, 1, acc0);  FITER(1, 9, 2, 1, acc1);
        FITER(0,10, 2, 1, acc0);  FITER(1,11, 2, 1, acc1);
        FITER(0,12, 2, 1, acc0);  FITER(1,13, 2, 1, acc1);
        FITER(0,14, 2, 0, acc0);  FITER(1,15, 0, 0, acc1);
        #undef FITER

        f32x4 acc;
        acc[0] = acc0[0] + acc1[0]; acc[1] = acc0[1] + acc1[1];
        acc[2] = acc0[2] + acc1[2]; acc[3] = acc0[3] + acc1[3];

        const int rb = akg * 4;
        float o0 = acc[0], o1 = acc[1], o2 = acc[2], o3 = acc[3];
        #pragma unroll 8
        for (int v = 0; v < NV; ++v) {
            float ev = ev_g[v * DD + dcol];
            o0 += w_lds[(rb + 0) * NV + v] * ev;
            o1 += w_lds[(rb + 1) * NV + v] * ev;
            o2 += w_lds[(rb + 2) * NV + v] * ev;
            o3 += w_lds[(rb + 3) * NV + v] * ev;
        }
        float* op = out_g + ((size_t)bh * TT + q0 + rb) * DD + dcol;
        op[0 * DD] = o0 * inv_lds[rb + 0];
        op[1 * DD] = o1 * inv_lds[rb + 1];
        op[2 * DD] = o2 * inv_lds[rb + 2];
        op[3 * DD] = o3 * inv_lds[rb + 3];
    }

    // ---- D2: normalized attn write (nontemporal, coalesced) ----
    {
        float* ab = attn_g + ((size_t)bh * TT + q0) * TT;
        #pragma unroll
        for (int j = 0; j < 4; ++j) {
            const int r = wave * 4 + j;
            const float inv = inv_lds[r];
            const int X = (r & 7) << 4;
            #pragma unroll
            for (int i = 0; i < 4; ++i) {
                bf16x4 p4 = *(const bf16x4*)(pbuf + r * 2048 + ((8 * lane + 512 * i) ^ X));
                f32x4 o;
                o[0] = bf2f(p4[0]) * inv; o[1] = bf2f(p4[1]) * inv;
                o[2] = bf2f(p4[2]) * inv; o[3] = bf2f(p4[3]) * inv;
                __builtin_nontemporal_store(o, (f32x4*)(ab + (size_t)r * TT + lane * 4 + 256 * i));
            }
        }
    }
}

extern "C" void kernel_launch(void* const* d_in, const int* in_sizes, int n_in,
                              void* d_out, int out_size, void* d_ws, size_t ws_size,
                              hipStream_t stream) {
    const float* q  = (const float*)d_in[0];
    const float* k  = (const float*)d_in[1];
    const float* v  = (const float*)d_in[2];
    const float* ek = (const float*)d_in[3];
    const float* ev = (const float*)d_in[4];
    float* out  = (float*)d_out;
    float* attn = out + (size_t)BH * TT * DD;

    short* kbuf = (short*)d_ws;
    short* vtb  = kbuf + (size_t)BH * TT * DD;

    convk_kernel<<<dim3(2048), dim3(256), 0, stream>>>(k, kbuf);
    transv_kernel<<<dim3(1024), dim3(256), 0, stream>>>(v, vtb);
    relattn_kernel<<<dim3(4096), dim3(256), 0, stream>>>(q, kbuf, vtb, ek, ev, out, attn);
}